// Round 15
// baseline (637.666 us; speedup 1.0000x reference)
//
#include <hip/hip_runtime.h>
#include <hip/hip_bf16.h>

// R15: fuse BN column-stats into gather epilogue (LDS block reduction ->
// 32-way-replicated global atomic flush; gemm64 prologue reduces replicas).
// Removes both post-gather bnstats dispatches (2 launches + 25.6 MB reads).
// Everything else identical to R14 (604us best: 128-node buckets, bf16
// intermediates, w15 edata, gather3 8-edge MLP).

#define NN 100000
#define NE 3200000
#define INV_N (1.0f/100000.0f)
#define BN_EPS 1e-5f
#define NBK 782            // buckets of 128 nodes
#define NSB 512            // scatter/hist blocks
#define EPB 6250           // edges per scatter/hist block (NSB*EPB == NE)
#define CAPB 6144          // LDS staging per bucket (mean 4092 + 32 sigma)
#define NREP 32            // stats replication factor

static __device__ __forceinline__ float bf2f(unsigned short u) {
    if ((u & 0x7f80u) == 0x7f80u) u = 0;          // inf/NaN -> 0 (input scrub)
    union { unsigned int i; float f; } z; z.i = ((unsigned int)u) << 16; return z.f;
}
static __device__ __forceinline__ float scrubf(float v) {
    return (fabsf(v) < 1e30f) ? v : 0.f;
}
static __device__ __forceinline__ unsigned short f2bf(float v) {
    union { float f; unsigned int i; } z; z.f = v;
    unsigned int lsb = (z.i >> 16) & 1u; z.i += 0x7fffu + lsb;
    return (unsigned short)(z.i >> 16);
}
static __device__ __forceinline__ float ld1(const void* p, size_t i, int f) {
    return f ? scrubf(((const float*)p)[i]) : bf2f(((const unsigned short*)p)[i]);
}
static __device__ __forceinline__ float4 ld4(const void* p, size_t g, int f) {
    if (f) { float4 v = ((const float4*)p)[g];
             return make_float4(scrubf(v.x),scrubf(v.y),scrubf(v.z),scrubf(v.w)); }
    ushort4 u = ((const ushort4*)p)[g];
    return make_float4(bf2f(u.x),bf2f(u.y),bf2f(u.z),bf2f(u.w));
}
static __device__ __forceinline__ int getidx(const int* ei, size_t pos, int i64) {
    return i64 ? ei[2*pos] : ei[pos];
}
static __device__ __forceinline__ float blo(unsigned v) {
    union { unsigned u; float f; } z; z.u = v << 16; return z.f;
}
static __device__ __forceinline__ float bhi(unsigned v) {
    union { unsigned u; float f; } z; z.u = v & 0xffff0000u; return z.f;
}
static __device__ __forceinline__ unsigned w15of(unsigned wu) {
    unsigned lsb = (wu >> 17) & 1u;
    return ((wu + 0xFFFFu + lsb) >> 17) & 0x7fffu;
}

// ---------------- detector + stats-buffer zero ----------------
// sums layout (floats): [0, 32*128)      layer-1 replicated stats
//                       [4096, 2*32*128) layer-2 replicated stats
//                       [8192, 8320)     bn3 stats (non-replicated)
__global__ void k_detect2(const unsigned short* __restrict__ x,
                          const int* __restrict__ ei, int* __restrict__ flag,
                          float* __restrict__ sums) {
    __shared__ int cnt[256];
    int tid = threadIdx.x, c = 0;
    for (int i = tid; i < 1024; i += 256) {
        unsigned short u = x[i];
        int ex = (u >> 7) & 0xff;
        if ((u & 0x7fffu) != 0 && (ex >= 0xB0 || ex <= 0x40)) c++;
    }
    cnt[tid] = c; __syncthreads();
    if (tid == 0) { int t = 0; for (int i = 0; i < 256; ++i) t += cnt[i];
                    flag[0] = (t > 64) ? 1 : 0; }
    if (tid == 1) { int nz = 0; for (int i = 1; i < 64; i += 2) nz |= ei[i];
                    flag[1] = (nz == 0) ? 1 : 0; }
    for (int i = tid; i < 2*NREP*128 + 128; i += 256) sums[i] = 0.f;
}

// ================= bucket counting sort (no global atomics) =================

__global__ __launch_bounds__(256) void k_hist(const int* __restrict__ flag,
                                              const int* __restrict__ ei,
                                              int* __restrict__ histmat) {
    __shared__ int hh[NBK];
    const int i64 = flag[1];
    const int blk = blockIdx.x, tid = threadIdx.x;
    for (int b = tid; b < NBK; b += 256) hh[b] = 0;
    __syncthreads();
    const size_t e0 = (size_t)blk * EPB;
    for (int e = tid; e < EPB; e += 256) {
        unsigned d = (unsigned)getidx(ei, NE + e0 + e, i64);
        if (d < NN) atomicAdd(&hh[d >> 7], 1);
    }
    __syncthreads();
    for (int b = tid; b < NBK; b += 256) histmat[blk*NBK + b] = hh[b];
}

__global__ __launch_bounds__(256) void k_scanA(int* __restrict__ histmat,
                                               int* __restrict__ btot) {
    __shared__ int sd[256];
    const int b = blockIdx.x, t = threadIdx.x;
    int v0 = histmat[(2*t)*NBK + b];
    int v1 = histmat[(2*t+1)*NBK + b];
    int ts = v0 + v1;
    sd[t] = ts; __syncthreads();
    #pragma unroll
    for (int ofs = 1; ofs < 256; ofs <<= 1) {
        int a = (t >= ofs) ? sd[t-ofs] : 0;
        __syncthreads(); sd[t] += a; __syncthreads();
    }
    int excl = sd[t] - ts;
    histmat[(2*t)*NBK + b]   = excl;
    histmat[(2*t+1)*NBK + b] = excl + v0;
    if (t == 255) btot[b] = sd[255];
}

__global__ void k_scanB(const int* __restrict__ btot, int* __restrict__ bstart) {
    __shared__ int sd[1024];
    int t = threadIdx.x;                 // 1024 threads; NBK=782 < 1024
    int v = (t < NBK) ? btot[t] : 0;
    sd[t] = v; __syncthreads();
    #pragma unroll
    for (int ofs = 1; ofs < 1024; ofs <<= 1) {
        int a = (t >= ofs) ? sd[t-ofs] : 0;
        __syncthreads(); sd[t] += a; __syncthreads();
    }
    if (t <= NBK) bstart[t] = sd[t] - v;   // exclusive; bstart[NBK] = total
}

__global__ __launch_bounds__(256) void k_scatter(
    const int* __restrict__ flag, const int* __restrict__ ei,
    const void* __restrict__ ew, const int* __restrict__ histmat,
    const int* __restrict__ bstart, int2* __restrict__ scr) {
    __shared__ int cursor[NBK];
    const int f = flag[0], i64 = flag[1];
    const int blk = blockIdx.x, tid = threadIdx.x;
    for (int b = tid; b < NBK; b += 256)
        cursor[b] = histmat[blk*NBK + b] + bstart[b];
    __syncthreads();
    const size_t e0 = (size_t)blk * EPB;
    for (int e = tid; e < EPB; e += 256) {
        unsigned d = (unsigned)getidx(ei, NE + e0 + e, i64);
        if (d >= NN) continue;
        unsigned s = (unsigned)getidx(ei, e0 + e, i64);
        float w = ld1(ew, e0 + e, f);
        if (s >= NN) { s = 0; w = 0.f; }
        int pos = atomicAdd(&cursor[d >> 7], 1);
        scr[pos] = make_int2((int)(((d & 127u) << 17) | s), __float_as_int(w));
    }
}

// fused node-sort + degree over 128-node buckets; w15 staged in LDS;
// coalesced edata write. Overflow (> CAPB, never here): scattered-write path.
__global__ __launch_bounds__(256) void k_sortdeg(
    const int* __restrict__ bstart, const int2* __restrict__ scr,
    unsigned* __restrict__ edata, int* __restrict__ rowptr, float* __restrict__ dis) {
    __shared__ unsigned sp[CAPB];
    __shared__ unsigned out[CAPB];
    __shared__ unsigned short sww[CAPB];
    __shared__ int cnt[128], scn[128], cur[128];
    __shared__ float degf[128];
    const int b = blockIdx.x, tid = threadIdx.x;
    const int node0 = b * 128;
    const int r0 = bstart[b], r1 = bstart[b+1], n = r1 - r0;
    const bool fit = (n <= CAPB);

    if (tid < 128) { cnt[tid] = 0; degf[tid] = 1.0f; }
    __syncthreads();
    if (fit) {
        for (int j = tid; j < n; j += 256) {
            int2 m = scr[r0 + j];
            sp[j] = (unsigned)m.x;
            sww[j] = (unsigned short)w15of((unsigned)m.y);
            int l = (m.x >> 17) & 127;
            atomicAdd(&cnt[l], 1);
            atomicAdd(&degf[l], __int_as_float(m.y));
        }
    } else {
        for (int j = tid; j < n; j += 256) {
            int2 m = scr[r0 + j];
            int l = (m.x >> 17) & 127;
            atomicAdd(&cnt[l], 1);
            atomicAdd(&degf[l], __int_as_float(m.y));
        }
    }
    __syncthreads();
    if (tid < 128) scn[tid] = cnt[tid];
    __syncthreads();
    #pragma unroll
    for (int ofs = 1; ofs < 128; ofs <<= 1) {
        int a = 0;
        if (tid < 128 && tid >= ofs) a = scn[tid - ofs];
        __syncthreads();
        if (tid < 128) scn[tid] += a;
        __syncthreads();
    }
    if (tid < 128) {
        int excl = scn[tid] - cnt[tid];
        cur[tid] = excl;
        int node = node0 + tid;
        if (node <= NN) rowptr[node] = r0 + excl;
        if (node <  NN) dis[node] = rsqrtf(fmaxf(degf[tid], 1e-12f));
    }
    __syncthreads();
    if (fit) {
        for (int j = tid; j < n; j += 256) {
            unsigned p = sp[j];
            int l = (p >> 17) & 127;
            int pos = atomicAdd(&cur[l], 1);
            out[pos] = (p & 0x1ffffu) | ((unsigned)sww[j] << 17);
        }
        __syncthreads();
        for (int j = tid; j < n; j += 256)           // coalesced linear write
            edata[r0 + j] = out[j];
    } else {
        for (int j = tid; j < n; j += 256) {
            int2 m = scr[r0 + j];
            int l = (m.x >> 17) & 127;
            int pos = atomicAdd(&cur[l], 1);
            edata[r0 + pos] = ((unsigned)m.x & 0x1ffffu) | (w15of((unsigned)m.y) << 17);
        }
    }
}

// gather + fused BN stats: wave per node; h bf16 pre-scaled by dis[src];
// coef = w15*dis[dst]; 8 edges in flight; agg written bf16.
// Stats (optionally post-relu) -> LDS block reduction -> replicated atomics.
template<int RELU>
__global__ __launch_bounds__(256) void k_gather3(
    const int* __restrict__ flag, const int* __restrict__ rowptr,
    const int* __restrict__ bstart, const unsigned* __restrict__ edata,
    const float* __restrict__ dis, const void* __restrict__ bias,
    const unsigned short* __restrict__ h, unsigned* __restrict__ aggB,
    float* __restrict__ sumout) {
    __shared__ float bsum[64], bsq[64];
    const int f = flag[0];
    const int tid = threadIdx.x;
    const int node = blockIdx.x * 4 + (tid >> 6);  // grid exact NN/4
    const int lane = tid & 63;
    const int li = lane & 31, hi = lane >> 5;
    if (tid < 64) { bsum[tid] = 0.f; bsq[tid] = 0.f; }
    const float d2 = dis[node];
    const unsigned* h32 = (const unsigned*)h;
    float a0 = 0.f, a1 = 0.f;
    if (hi == 0) {
        unsigned hv = h32[(size_t)node*32 + li];      // h' = dis*h -> d2*h'
        a0 = ld1(bias, 2*li,   f) + d2 * blo(hv);
        a1 = ld1(bias, 2*li+1, f) + d2 * bhi(hv);
    }
    int j = rowptr[node];
    const int end = ((node & 127) == 127) ? bstart[(node >> 7) + 1] : rowptr[node + 1];
    for (; j + 7 < end; j += 8) {
        unsigned m0 = edata[j +     hi];
        unsigned m1 = edata[j + 2 + hi];
        unsigned m2 = edata[j + 4 + hi];
        unsigned m3 = edata[j + 6 + hi];
        unsigned v0 = h32[(size_t)(m0 & 0x1ffffu)*32 + li];
        unsigned v1 = h32[(size_t)(m1 & 0x1ffffu)*32 + li];
        unsigned v2 = h32[(size_t)(m2 & 0x1ffffu)*32 + li];
        unsigned v3 = h32[(size_t)(m3 & 0x1ffffu)*32 + li];
        float c0 = __int_as_float((int)(m0 & 0xFFFE0000u)) * d2;
        float c1 = __int_as_float((int)(m1 & 0xFFFE0000u)) * d2;
        float c2 = __int_as_float((int)(m2 & 0xFFFE0000u)) * d2;
        float c3 = __int_as_float((int)(m3 & 0xFFFE0000u)) * d2;
        a0 = fmaf(c0, blo(v0), a0); a1 = fmaf(c0, bhi(v0), a1);
        a0 = fmaf(c1, blo(v1), a0); a1 = fmaf(c1, bhi(v1), a1);
        a0 = fmaf(c2, blo(v2), a0); a1 = fmaf(c2, bhi(v2), a1);
        a0 = fmaf(c3, blo(v3), a0); a1 = fmaf(c3, bhi(v3), a1);
    }
    for (; j + 1 < end; j += 2) {
        unsigned m0 = edata[j + hi];
        unsigned v0 = h32[(size_t)(m0 & 0x1ffffu)*32 + li];
        float c0 = __int_as_float((int)(m0 & 0xFFFE0000u)) * d2;
        a0 = fmaf(c0, blo(v0), a0); a1 = fmaf(c0, bhi(v0), a1);
    }
    if (j < end && hi == 0) {
        unsigned m0 = edata[j];
        unsigned v0 = h32[(size_t)(m0 & 0x1ffffu)*32 + li];
        float c0 = __int_as_float((int)(m0 & 0xFFFE0000u)) * d2;
        a0 = fmaf(c0, blo(v0), a0); a1 = fmaf(c0, bhi(v0), a1);
    }
    a0 += __shfl_xor(a0, 32);
    a1 += __shfl_xor(a1, 32);
    __syncthreads();                                  // bsum/bsq init visible
    if (hi == 0) {
        aggB[(size_t)node*32 + li] = (unsigned)f2bf(a0) | ((unsigned)f2bf(a1) << 16);
        float v0 = RELU ? fmaxf(a0, 0.f) : a0;
        float v1 = RELU ? fmaxf(a1, 0.f) : a1;
        atomicAdd(&bsum[2*li],   v0); atomicAdd(&bsq[2*li],   v0*v0);
        atomicAdd(&bsum[2*li+1], v1); atomicAdd(&bsq[2*li+1], v1*v1);
    }
    __syncthreads();
    if (tid < 64) {
        int rep = blockIdx.x & (NREP - 1);
        unsafeAtomicAdd(&sumout[rep*128 + tid],      bsum[tid]);
        unsafeAtomicAdd(&sumout[rep*128 + 64 + tid], bsq[tid]);
    }
}

// ================= dense kernels =================

__global__ __launch_bounds__(256) void k_gemm1(
    const int* __restrict__ flag, const void* __restrict__ x,
    const void* __restrict__ W, const void* __restrict__ bias,
    const float* __restrict__ dis, unsigned short* __restrict__ h_out) {
    __shared__ __align__(16) float ws[128*64];
    __shared__ __align__(16) float xs[64*64];
    const int f = flag[0];
    const int tid = threadIdx.x;
    const int rowbase = blockIdx.x * 64;
    #pragma unroll
    for (int it = 0; it < 8; ++it) {
        int g = it*256 + tid;
        float4 v = ld4(W, g, f);
        int b = g*4;
        ws[b]=v.x; ws[b+1]=v.y; ws[b+2]=v.z; ws[b+3]=v.w;
    }
    const int tr = (tid >> 4) << 2;
    const int tc = (tid & 15) << 2;
    const int row = tid & 63;
    const int grow = rowbase + row;
    const bool valid = grow < NN;
    float acc[4][4] = {};
    for (int half = 0; half < 2; ++half) {
        __syncthreads();
        #pragma unroll
        for (int it = 0; it < 4; ++it) {
            int f4 = (tid >> 6) + it*4;
            int kl = f4*4;
            float4 v = make_float4(0,0,0,0);
            if (valid) v = ld4(x, (size_t)grow*32 + half*16 + f4, f);
            xs[(kl+0)*64+row]=v.x; xs[(kl+1)*64+row]=v.y;
            xs[(kl+2)*64+row]=v.z; xs[(kl+3)*64+row]=v.w;
        }
        __syncthreads();
        #pragma unroll 8
        for (int k = 0; k < 64; ++k) {
            const float4 av = *(const float4*)&xs[k*64 + tr];
            const float4 wv = *(const float4*)&ws[(half*64 + k)*64 + tc];
            const float aa[4] = {av.x, av.y, av.z, av.w};
            const float ww[4] = {wv.x, wv.y, wv.z, wv.w};
            #pragma unroll
            for (int i = 0; i < 4; ++i)
                #pragma unroll
                for (int j = 0; j < 4; ++j)
                    acc[i][j] = fmaf(aa[i], ww[j], acc[i][j]);
        }
    }
    #pragma unroll
    for (int i = 0; i < 4; ++i) {
        int r = rowbase + tr + i;
        if (r < NN) {
            float hm = dis[r];
            ushort4 hv = make_ushort4(f2bf(acc[i][0]*hm), f2bf(acc[i][1]*hm),
                                      f2bf(acc[i][2]*hm), f2bf(acc[i][3]*hm));
            *(ushort4*)&h_out[(size_t)r*64 + tc] = hv;
        }
    }
}

// 64x64 GEMM, bf16 input with fused BN (+relu). insums is NREP-replicated.
template<bool RELU, bool AGG>
__global__ __launch_bounds__(256) void k_gemm64(
    const int* __restrict__ flag, const unsigned short* __restrict__ in,
    const void* __restrict__ W, const void* __restrict__ bias,
    const void* __restrict__ g, const void* __restrict__ bb,
    const float* __restrict__ insums, const float* __restrict__ dis,
    unsigned short* __restrict__ out_bf, float* __restrict__ outsums) {
    __shared__ __align__(16) float ws[64*64];
    __shared__ __align__(16) float xs[64*64];
    __shared__ float sc[64], sh[64];
    const int f = flag[0];
    const int tid = threadIdx.x;
    const int rowbase = blockIdx.x * 64;
    if (tid < 64) {
        float s = 0.f, q = 0.f;
        #pragma unroll
        for (int r = 0; r < NREP; ++r) {
            s += insums[r*128 + tid];
            q += insums[r*128 + 64 + tid];
        }
        float mean = s * INV_N;
        float var  = fmaxf(q * INV_N - mean*mean, 0.f);
        float sc_  = ld1(g, tid, f) * rsqrtf(var + BN_EPS);
        sc[tid] = sc_;
        sh[tid] = ld1(bb, tid, f) - mean*sc_;
    }
    #pragma unroll
    for (int it = 0; it < 4; ++it) {
        int gi = it*256 + tid;
        float4 v = ld4(W, gi, f);
        int b = gi*4;
        ws[b]=v.x; ws[b+1]=v.y; ws[b+2]=v.z; ws[b+3]=v.w;
    }
    __syncthreads();
    {
        int row = tid & 63;
        int grow = rowbase + row;
        bool valid = grow < NN;
        #pragma unroll
        for (int it = 0; it < 4; ++it) {
            int f4 = (tid >> 6) + it*4;
            int k = f4*4;
            float a0=0,a1=0,a2=0,a3=0;
            if (valid) {
                ushort4 u = *(const ushort4*)&in[(size_t)grow*64 + k];
                a0=bf2f(u.x); a1=bf2f(u.y); a2=bf2f(u.z); a3=bf2f(u.w);
            }
            if (RELU) { a0=fmaxf(a0,0.f); a1=fmaxf(a1,0.f); a2=fmaxf(a2,0.f); a3=fmaxf(a3,0.f); }
            a0 = a0*sc[k+0]+sh[k+0]; a1 = a1*sc[k+1]+sh[k+1];
            a2 = a2*sc[k+2]+sh[k+2]; a3 = a3*sc[k+3]+sh[k+3];
            xs[(k+0)*64+row]=a0; xs[(k+1)*64+row]=a1;
            xs[(k+2)*64+row]=a2; xs[(k+3)*64+row]=a3;
        }
    }
    __syncthreads();
    const int tr = (tid >> 4) << 2;
    const int tc = (tid & 15) << 2;
    float acc[4][4] = {};
    #pragma unroll 8
    for (int k = 0; k < 64; ++k) {
        const float4 av = *(const float4*)&xs[k*64 + tr];
        const float4 wv = *(const float4*)&ws[k*64 + tc];
        const float aa[4] = {av.x, av.y, av.z, av.w};
        const float ww[4] = {wv.x, wv.y, wv.z, wv.w};
        #pragma unroll
        for (int i = 0; i < 4; ++i)
            #pragma unroll
            for (int j = 0; j < 4; ++j)
                acc[i][j] = fmaf(aa[i], ww[j], acc[i][j]);
    }
    float bc[4];
    #pragma unroll
    for (int j = 0; j < 4; ++j) bc[j] = ld1(bias, tc+j, f);
    if (AGG) {
        #pragma unroll
        for (int i = 0; i < 4; ++i) {
            int r = rowbase + tr + i;
            if (r < NN) {
                float hm = dis[r];
                ushort4 hv = make_ushort4(f2bf(acc[i][0]*hm), f2bf(acc[i][1]*hm),
                                          f2bf(acc[i][2]*hm), f2bf(acc[i][3]*hm));
                *(ushort4*)&out_bf[(size_t)r*64 + tc] = hv;
            }
        }
    } else {
        float ps[4] = {0,0,0,0}, pq[4] = {0,0,0,0};
        #pragma unroll
        for (int i = 0; i < 4; ++i) {
            int r = rowbase + tr + i;
            if (r < NN) {
                float y0 = acc[i][0]+bc[0], y1 = acc[i][1]+bc[1];
                float y2 = acc[i][2]+bc[2], y3 = acc[i][3]+bc[3];
                *(ushort4*)&out_bf[(size_t)r*64 + tc] =
                    make_ushort4(f2bf(y0), f2bf(y1), f2bf(y2), f2bf(y3));
                ps[0]+=y0; ps[1]+=y1; ps[2]+=y2; ps[3]+=y3;
                pq[0]+=y0*y0; pq[1]+=y1*y1; pq[2]+=y2*y2; pq[3]+=y3*y3;
            }
        }
        __syncthreads();
        int grp = tid >> 4;
        #pragma unroll
        for (int j = 0; j < 4; ++j) { xs[grp*64 + tc+j] = ps[j]; ws[grp*64 + tc+j] = pq[j]; }
        __syncthreads();
        if (tid < 64) {
            float s = 0.f, q = 0.f;
            #pragma unroll
            for (int g2 = 0; g2 < 16; ++g2) { s += xs[g2*64+tid]; q += ws[g2*64+tid]; }
            unsafeAtomicAdd(&outsums[tid], s);
            unsafeAtomicAdd(&outsums[64+tid], q);
        }
    }
}

// final: out = bn3(y3_bf16) @ lin2_W + lin2_b  (sums non-replicated)
__global__ __launch_bounds__(256) void k_final(
    const int* __restrict__ flag, const unsigned short* __restrict__ y3,
    const void* __restrict__ g, const void* __restrict__ bb,
    const float* __restrict__ sums, const void* __restrict__ w2,
    const void* __restrict__ b2, void* __restrict__ out) {
    __shared__ __align__(16) float tile[64*64];
    __shared__ float wp[64], tv[64];
    const int f = flag[0];
    const int tid = threadIdx.x;
    const int base = blockIdx.x * 64;
    if (tid < 64) {
        float mean = sums[tid] * INV_N;
        float var  = fmaxf(sums[64+tid] * INV_N - mean*mean, 0.f);
        float s = ld1(g, tid, f) * rsqrtf(var + BN_EPS);
        float t = ld1(bb, tid, f) - mean*s;
        float w = ld1(w2, tid, f);
        wp[tid] = s*w; tv[tid] = t*w;
    }
    #pragma unroll
    for (int it = 0; it < 4; ++it) {
        int i4 = it*256 + tid;
        int row = i4 >> 4, c4 = (i4 & 15)*4;
        float4 v = make_float4(0,0,0,0);
        if (base + row < NN) {
            ushort4 u = *(const ushort4*)&y3[(size_t)(base+row)*64 + c4];
            v = make_float4(bf2f(u.x), bf2f(u.y), bf2f(u.z), bf2f(u.w));
        }
        *(float4*)&tile[row*64 + c4] = v;
    }
    __syncthreads();
    if (tid < 64 && base + tid < NN) {
        float a = ld1(b2, 0, f);
        #pragma unroll
        for (int c = 0; c < 64; ++c) a += tv[c];
        #pragma unroll
        for (int cc = 0; cc < 64; ++cc) {
            int c = (cc + tid) & 63;
            a += tile[tid*64 + c] * wp[c];
        }
        if (f) ((float*)out)[base + tid] = a;
        else   ((unsigned short*)out)[base + tid] = f2bf(a);
    }
}

extern "C" void kernel_launch(void* const* d_in, const int* in_sizes, int n_in,
                              void* d_out, int out_size, void* d_ws, size_t ws_size,
                              hipStream_t stream) {
    const unsigned short* x = (const unsigned short*)d_in[0];
    const void* ew  = d_in[1];
    const void* W1  = d_in[2];
    const void* b1  = d_in[3];
    const void* W2  = d_in[4];
    const void* b2  = d_in[5];
    const void* l1W = d_in[6];
    const void* l1b = d_in[7];
    const void* l2W = d_in[8];
    const void* l2b = d_in[9];
    const void* g1  = d_in[10];
    const void* bb1 = d_in[11];
    const void* g2  = d_in[12];
    const void* bb2 = d_in[13];
    const void* g3  = d_in[14];
    const void* bb3 = d_in[15];
    const int* eidx = (const int*)d_in[16];

    // layout (float idx): flag 0..16, dis 400..100400;
    // region 100400..6500400: scr(int2) during preprocessing, then aggB (bf16)
    // hbuf(bf16) 6500400..9700400, histmat/rowptr 9700400, btot 10500656,
    // bstart 10502224, edata 10503792..13703792,
    // sums (replicated stats) 13703792..13712112. Need 54.85 MB (proven).
    int*   flag = (int*)d_ws;
    float* wsf  = (float*)d_ws;
    float* dis  = wsf + 400;
    unsigned*       aggB = (unsigned*)(wsf + 100400);
    unsigned short* aggS = (unsigned short*)(wsf + 100400);
    unsigned short* hbuf = (unsigned short*)(wsf + 6500400);
    int*      histmat = (int*)(wsf + 9700400);
    int*      rowptr2 = histmat;
    int*      btot    = (int*)(wsf + 10500656);
    int*      bstart  = (int*)(wsf + 10502224);
    unsigned* edata   = (unsigned*)(wsf + 10503792);
    float*    sums    = wsf + 13703792;           // 2*NREP*128 + 128 floats
    int2*     scr     = (int2*)(wsf + 100400);
    const size_t NEED = (size_t)13712112 * 4;
    if (ws_size < NEED) return;

    float* sumsL1 = sums;
    float* sumsL2 = sums + NREP*128;
    float* sums3  = sums + 2*NREP*128;

    k_detect2  <<<1, 256, 0, stream>>>(x, eidx, flag, sums);
    k_hist     <<<NSB, 256, 0, stream>>>(flag, eidx, histmat);
    k_scanA    <<<NBK, 256, 0, stream>>>(histmat, btot);
    k_scanB    <<<1, 1024, 0, stream>>>(btot, bstart);
    k_scatter  <<<NSB, 256, 0, stream>>>(flag, eidx, ew, histmat, bstart, scr);
    k_sortdeg  <<<NBK, 256, 0, stream>>>(bstart, scr, edata, rowptr2, dis);
    // layer 1 (gather also emits relu'ed BN stats)
    k_gemm1    <<<1563, 256, 0, stream>>>(flag, x, W1, b1, dis, hbuf);
    k_gather3<1><<<NN/4, 256, 0, stream>>>(flag, rowptr2, bstart, edata,
                                           dis, b1, hbuf, aggB, sumsL1);
    // layer 2 (gather emits raw BN stats)
    k_gemm64<true, true><<<1563, 256, 0, stream>>>(flag, aggS, W2, b2, g1, bb1,
                                                   sumsL1, dis, hbuf, nullptr);
    k_gather3<0><<<NN/4, 256, 0, stream>>>(flag, rowptr2, bstart, edata,
                                           dis, b2, hbuf, aggB, sumsL2);
    // lin1 (+ bn3 stats), y3 bf16 in place over agg2
    k_gemm64<false, false><<<1563, 256, 0, stream>>>(flag, aggS, l1W, l1b, g2, bb2,
                                                     sumsL2, dis, aggS, sums3);
    k_final    <<<1563, 256, 0, stream>>>(flag, aggS, g3, bb3, sums3, l2W, l2b, d_out);
}

// Round 16
// 602.702 us; speedup vs baseline: 1.0580x; 1.0580x over previous
//
#include <hip/hip_runtime.h>
#include <hip/hip_bf16.h>

// R16 = R14 exact revert (603.9us best). R15's fused BN-stats regressed
// gather 94->137us: the added block-wide __syncthreads coupled 4 previously
// independent waves to the slowest node's degree tail. Final configuration:
// - zero-global-atomic preprocessing (LDS counting sort, 128-node buckets)
// - w15-packed 4B edata, h bf16 pre-scaled by dis[src]
// - wave-per-node register gather, 8 edges in flight
// - bf16 intermediates, BN/relu/bias fused into GEMMs

#define NN 100000
#define NE 3200000
#define INV_N (1.0f/100000.0f)
#define BN_EPS 1e-5f
#define NBK 782            // buckets of 128 nodes
#define NSB 512            // scatter/hist blocks
#define EPB 6250           // edges per scatter/hist block (NSB*EPB == NE)
#define CAPB 6144          // LDS staging per bucket (mean 4092 + 32 sigma)

static __device__ __forceinline__ float bf2f(unsigned short u) {
    if ((u & 0x7f80u) == 0x7f80u) u = 0;          // inf/NaN -> 0 (input scrub)
    union { unsigned int i; float f; } z; z.i = ((unsigned int)u) << 16; return z.f;
}
static __device__ __forceinline__ float scrubf(float v) {
    return (fabsf(v) < 1e30f) ? v : 0.f;
}
static __device__ __forceinline__ unsigned short f2bf(float v) {
    union { float f; unsigned int i; } z; z.f = v;
    unsigned int lsb = (z.i >> 16) & 1u; z.i += 0x7fffu + lsb;
    return (unsigned short)(z.i >> 16);
}
static __device__ __forceinline__ float ld1(const void* p, size_t i, int f) {
    return f ? scrubf(((const float*)p)[i]) : bf2f(((const unsigned short*)p)[i]);
}
static __device__ __forceinline__ float4 ld4(const void* p, size_t g, int f) {
    if (f) { float4 v = ((const float4*)p)[g];
             return make_float4(scrubf(v.x),scrubf(v.y),scrubf(v.z),scrubf(v.w)); }
    ushort4 u = ((const ushort4*)p)[g];
    return make_float4(bf2f(u.x),bf2f(u.y),bf2f(u.z),bf2f(u.w));
}
static __device__ __forceinline__ int getidx(const int* ei, size_t pos, int i64) {
    return i64 ? ei[2*pos] : ei[pos];
}
static __device__ __forceinline__ float blo(unsigned v) {
    union { unsigned u; float f; } z; z.u = v << 16; return z.f;
}
static __device__ __forceinline__ float bhi(unsigned v) {
    union { unsigned u; float f; } z; z.u = v & 0xffff0000u; return z.f;
}
static __device__ __forceinline__ unsigned w15of(unsigned wu) {
    unsigned lsb = (wu >> 17) & 1u;
    return ((wu + 0xFFFFu + lsb) >> 17) & 0x7fffu;
}

// ---------------- detector + sums zero ----------------
__global__ void k_detect2(const unsigned short* __restrict__ x,
                          const int* __restrict__ ei, int* __restrict__ flag,
                          float* __restrict__ sums) {
    __shared__ int cnt[256];
    int tid = threadIdx.x, c = 0;
    for (int i = tid; i < 1024; i += 256) {
        unsigned short u = x[i];
        int ex = (u >> 7) & 0xff;
        if ((u & 0x7fffu) != 0 && (ex >= 0xB0 || ex <= 0x40)) c++;
    }
    cnt[tid] = c; __syncthreads();
    if (tid == 0) { int t = 0; for (int i = 0; i < 256; ++i) t += cnt[i];
                    flag[0] = (t > 64) ? 1 : 0; }
    if (tid == 1) { int nz = 0; for (int i = 1; i < 64; i += 2) nz |= ei[i];
                    flag[1] = (nz == 0) ? 1 : 0; }
    if (tid < 128) { sums[tid]=0.f; sums[128+tid]=0.f; sums[256+tid]=0.f; }
}

// ================= bucket counting sort (no global atomics) =================

__global__ __launch_bounds__(256) void k_hist(const int* __restrict__ flag,
                                              const int* __restrict__ ei,
                                              int* __restrict__ histmat) {
    __shared__ int hh[NBK];
    const int i64 = flag[1];
    const int blk = blockIdx.x, tid = threadIdx.x;
    for (int b = tid; b < NBK; b += 256) hh[b] = 0;
    __syncthreads();
    const size_t e0 = (size_t)blk * EPB;
    for (int e = tid; e < EPB; e += 256) {
        unsigned d = (unsigned)getidx(ei, NE + e0 + e, i64);
        if (d < NN) atomicAdd(&hh[d >> 7], 1);
    }
    __syncthreads();
    for (int b = tid; b < NBK; b += 256) histmat[blk*NBK + b] = hh[b];
}

// per-bucket column scan across the NSB=512 blocks (exclusive), total -> btot
__global__ __launch_bounds__(256) void k_scanA(int* __restrict__ histmat,
                                               int* __restrict__ btot) {
    __shared__ int sd[256];
    const int b = blockIdx.x, t = threadIdx.x;
    int v0 = histmat[(2*t)*NBK + b];
    int v1 = histmat[(2*t+1)*NBK + b];
    int ts = v0 + v1;
    sd[t] = ts; __syncthreads();
    #pragma unroll
    for (int ofs = 1; ofs < 256; ofs <<= 1) {
        int a = (t >= ofs) ? sd[t-ofs] : 0;
        __syncthreads(); sd[t] += a; __syncthreads();
    }
    int excl = sd[t] - ts;
    histmat[(2*t)*NBK + b]   = excl;
    histmat[(2*t+1)*NBK + b] = excl + v0;
    if (t == 255) btot[b] = sd[255];
}

__global__ void k_scanB(const int* __restrict__ btot, int* __restrict__ bstart) {
    __shared__ int sd[1024];
    int t = threadIdx.x;                 // 1024 threads; NBK=782 < 1024
    int v = (t < NBK) ? btot[t] : 0;
    sd[t] = v; __syncthreads();
    #pragma unroll
    for (int ofs = 1; ofs < 1024; ofs <<= 1) {
        int a = (t >= ofs) ? sd[t-ofs] : 0;
        __syncthreads(); sd[t] += a; __syncthreads();
    }
    if (t <= NBK) bstart[t] = sd[t] - v;   // exclusive; bstart[NBK] = total
}

__global__ __launch_bounds__(256) void k_scatter(
    const int* __restrict__ flag, const int* __restrict__ ei,
    const void* __restrict__ ew, const int* __restrict__ histmat,
    const int* __restrict__ bstart, int2* __restrict__ scr) {
    __shared__ int cursor[NBK];
    const int f = flag[0], i64 = flag[1];
    const int blk = blockIdx.x, tid = threadIdx.x;
    for (int b = tid; b < NBK; b += 256)
        cursor[b] = histmat[blk*NBK + b] + bstart[b];
    __syncthreads();
    const size_t e0 = (size_t)blk * EPB;
    for (int e = tid; e < EPB; e += 256) {
        unsigned d = (unsigned)getidx(ei, NE + e0 + e, i64);
        if (d >= NN) continue;
        unsigned s = (unsigned)getidx(ei, e0 + e, i64);
        float w = ld1(ew, e0 + e, f);
        if (s >= NN) { s = 0; w = 0.f; }
        int pos = atomicAdd(&cursor[d >> 7], 1);
        scr[pos] = make_int2((int)(((d & 127u) << 17) | s), __float_as_int(w));
    }
}

// fused node-sort + degree over 128-node buckets; w15 staged in LDS;
// coalesced edata write. Overflow (> CAPB, never here): scattered-write path.
__global__ __launch_bounds__(256) void k_sortdeg(
    const int* __restrict__ bstart, const int2* __restrict__ scr,
    unsigned* __restrict__ edata, int* __restrict__ rowptr, float* __restrict__ dis) {
    __shared__ unsigned sp[CAPB];
    __shared__ unsigned out[CAPB];
    __shared__ unsigned short sww[CAPB];
    __shared__ int cnt[128], scn[128], cur[128];
    __shared__ float degf[128];
    const int b = blockIdx.x, tid = threadIdx.x;
    const int node0 = b * 128;
    const int r0 = bstart[b], r1 = bstart[b+1], n = r1 - r0;
    const bool fit = (n <= CAPB);

    if (tid < 128) { cnt[tid] = 0; degf[tid] = 1.0f; }
    __syncthreads();
    if (fit) {
        for (int j = tid; j < n; j += 256) {
            int2 m = scr[r0 + j];
            sp[j] = (unsigned)m.x;
            sww[j] = (unsigned short)w15of((unsigned)m.y);
            int l = (m.x >> 17) & 127;
            atomicAdd(&cnt[l], 1);
            atomicAdd(&degf[l], __int_as_float(m.y));
        }
    } else {
        for (int j = tid; j < n; j += 256) {
            int2 m = scr[r0 + j];
            int l = (m.x >> 17) & 127;
            atomicAdd(&cnt[l], 1);
            atomicAdd(&degf[l], __int_as_float(m.y));
        }
    }
    __syncthreads();
    if (tid < 128) scn[tid] = cnt[tid];
    __syncthreads();
    #pragma unroll
    for (int ofs = 1; ofs < 128; ofs <<= 1) {
        int a = 0;
        if (tid < 128 && tid >= ofs) a = scn[tid - ofs];
        __syncthreads();
        if (tid < 128) scn[tid] += a;
        __syncthreads();
    }
    if (tid < 128) {
        int excl = scn[tid] - cnt[tid];
        cur[tid] = excl;
        int node = node0 + tid;
        if (node <= NN) rowptr[node] = r0 + excl;
        if (node <  NN) dis[node] = rsqrtf(fmaxf(degf[tid], 1e-12f));
    }
    __syncthreads();
    if (fit) {
        for (int j = tid; j < n; j += 256) {
            unsigned p = sp[j];
            int l = (p >> 17) & 127;
            int pos = atomicAdd(&cur[l], 1);
            out[pos] = (p & 0x1ffffu) | ((unsigned)sww[j] << 17);
        }
        __syncthreads();
        for (int j = tid; j < n; j += 256)           // coalesced linear write
            edata[r0 + j] = out[j];
    } else {
        for (int j = tid; j < n; j += 256) {
            int2 m = scr[r0 + j];
            int l = (m.x >> 17) & 127;
            int pos = atomicAdd(&cur[l], 1);
            edata[r0 + pos] = ((unsigned)m.x & 0x1ffffu) | (w15of((unsigned)m.y) << 17);
        }
    }
}

// gather: wave per node; h bf16 pre-scaled by dis[src]; coef = w15*dis[dst];
// 8 edges in flight (4 per half-wave); agg written bf16 (uint = 2 features).
__global__ __launch_bounds__(256) void k_gather3(
    const int* __restrict__ flag, const int* __restrict__ rowptr,
    const int* __restrict__ bstart, const unsigned* __restrict__ edata,
    const float* __restrict__ dis, const void* __restrict__ bias,
    const unsigned short* __restrict__ h, unsigned* __restrict__ aggB) {
    const int f = flag[0];
    const int node = blockIdx.x * 4 + (threadIdx.x >> 6);  // grid exact NN/4
    const int lane = threadIdx.x & 63;
    const int li = lane & 31, hi = lane >> 5;
    const float d2 = dis[node];
    const unsigned* h32 = (const unsigned*)h;
    float a0 = 0.f, a1 = 0.f;
    if (hi == 0) {
        unsigned hv = h32[(size_t)node*32 + li];      // h' = dis*h -> d2*h'
        a0 = ld1(bias, 2*li,   f) + d2 * blo(hv);
        a1 = ld1(bias, 2*li+1, f) + d2 * bhi(hv);
    }
    int j = rowptr[node];
    const int end = ((node & 127) == 127) ? bstart[(node >> 7) + 1] : rowptr[node + 1];
    for (; j + 7 < end; j += 8) {
        unsigned m0 = edata[j +     hi];
        unsigned m1 = edata[j + 2 + hi];
        unsigned m2 = edata[j + 4 + hi];
        unsigned m3 = edata[j + 6 + hi];
        unsigned v0 = h32[(size_t)(m0 & 0x1ffffu)*32 + li];
        unsigned v1 = h32[(size_t)(m1 & 0x1ffffu)*32 + li];
        unsigned v2 = h32[(size_t)(m2 & 0x1ffffu)*32 + li];
        unsigned v3 = h32[(size_t)(m3 & 0x1ffffu)*32 + li];
        float c0 = __int_as_float((int)(m0 & 0xFFFE0000u)) * d2;
        float c1 = __int_as_float((int)(m1 & 0xFFFE0000u)) * d2;
        float c2 = __int_as_float((int)(m2 & 0xFFFE0000u)) * d2;
        float c3 = __int_as_float((int)(m3 & 0xFFFE0000u)) * d2;
        a0 = fmaf(c0, blo(v0), a0); a1 = fmaf(c0, bhi(v0), a1);
        a0 = fmaf(c1, blo(v1), a0); a1 = fmaf(c1, bhi(v1), a1);
        a0 = fmaf(c2, blo(v2), a0); a1 = fmaf(c2, bhi(v2), a1);
        a0 = fmaf(c3, blo(v3), a0); a1 = fmaf(c3, bhi(v3), a1);
    }
    for (; j + 1 < end; j += 2) {
        unsigned m0 = edata[j + hi];
        unsigned v0 = h32[(size_t)(m0 & 0x1ffffu)*32 + li];
        float c0 = __int_as_float((int)(m0 & 0xFFFE0000u)) * d2;
        a0 = fmaf(c0, blo(v0), a0); a1 = fmaf(c0, bhi(v0), a1);
    }
    if (j < end && hi == 0) {
        unsigned m0 = edata[j];
        unsigned v0 = h32[(size_t)(m0 & 0x1ffffu)*32 + li];
        float c0 = __int_as_float((int)(m0 & 0xFFFE0000u)) * d2;
        a0 = fmaf(c0, blo(v0), a0); a1 = fmaf(c0, bhi(v0), a1);
    }
    a0 += __shfl_xor(a0, 32);
    a1 += __shfl_xor(a1, 32);
    if (hi == 0)
        aggB[(size_t)node*32 + li] = (unsigned)f2bf(a0) | ((unsigned)f2bf(a1) << 16);
}

// ================= dense kernels =================

__global__ __launch_bounds__(256) void k_gemm1(
    const int* __restrict__ flag, const void* __restrict__ x,
    const void* __restrict__ W, const void* __restrict__ bias,
    const float* __restrict__ dis, unsigned short* __restrict__ h_out) {
    __shared__ __align__(16) float ws[128*64];
    __shared__ __align__(16) float xs[64*64];
    const int f = flag[0];
    const int tid = threadIdx.x;
    const int rowbase = blockIdx.x * 64;
    #pragma unroll
    for (int it = 0; it < 8; ++it) {
        int g = it*256 + tid;
        float4 v = ld4(W, g, f);
        int b = g*4;
        ws[b]=v.x; ws[b+1]=v.y; ws[b+2]=v.z; ws[b+3]=v.w;
    }
    const int tr = (tid >> 4) << 2;
    const int tc = (tid & 15) << 2;
    const int row = tid & 63;
    const int grow = rowbase + row;
    const bool valid = grow < NN;
    float acc[4][4] = {};
    for (int half = 0; half < 2; ++half) {
        __syncthreads();
        #pragma unroll
        for (int it = 0; it < 4; ++it) {
            int f4 = (tid >> 6) + it*4;
            int kl = f4*4;
            float4 v = make_float4(0,0,0,0);
            if (valid) v = ld4(x, (size_t)grow*32 + half*16 + f4, f);
            xs[(kl+0)*64+row]=v.x; xs[(kl+1)*64+row]=v.y;
            xs[(kl+2)*64+row]=v.z; xs[(kl+3)*64+row]=v.w;
        }
        __syncthreads();
        #pragma unroll 8
        for (int k = 0; k < 64; ++k) {
            const float4 av = *(const float4*)&xs[k*64 + tr];
            const float4 wv = *(const float4*)&ws[(half*64 + k)*64 + tc];
            const float aa[4] = {av.x, av.y, av.z, av.w};
            const float ww[4] = {wv.x, wv.y, wv.z, wv.w};
            #pragma unroll
            for (int i = 0; i < 4; ++i)
                #pragma unroll
                for (int j = 0; j < 4; ++j)
                    acc[i][j] = fmaf(aa[i], ww[j], acc[i][j]);
        }
    }
    #pragma unroll
    for (int i = 0; i < 4; ++i) {
        int r = rowbase + tr + i;
        if (r < NN) {
            float hm = dis[r];
            ushort4 hv = make_ushort4(f2bf(acc[i][0]*hm), f2bf(acc[i][1]*hm),
                                      f2bf(acc[i][2]*hm), f2bf(acc[i][3]*hm));
            *(ushort4*)&h_out[(size_t)r*64 + tc] = hv;
        }
    }
}

// BN column stats over bf16 tensor (uint2 = 4 features); 512 blocks
__global__ __launch_bounds__(256) void k_bnstats_bf(const uint2* __restrict__ src,
                                                    float* __restrict__ sumout, int relu) {
    const int tid = threadIdx.x;
    float s0=0,s1=0,s2=0,s3=0, q0=0,q1=0,q2=0,q3=0;
    for (int g = blockIdx.x*256 + tid; g < NN*16; g += 512*256) {
        uint2 u = src[g];
        float vx = blo(u.x), vy = bhi(u.x), vz = blo(u.y), vw = bhi(u.y);
        if (relu) { vx=fmaxf(vx,0.f); vy=fmaxf(vy,0.f);
                    vz=fmaxf(vz,0.f); vw=fmaxf(vw,0.f); }
        s0+=vx; q0+=vx*vx; s1+=vy; q1+=vy*vy;
        s2+=vz; q2+=vz*vz; s3+=vw; q3+=vw*vw;
    }
    __shared__ float ls[1024], lq[1024];
    ls[tid*4+0]=s0; ls[tid*4+1]=s1; ls[tid*4+2]=s2; ls[tid*4+3]=s3;
    lq[tid*4+0]=q0; lq[tid*4+1]=q1; lq[tid*4+2]=q2; lq[tid*4+3]=q3;
    __syncthreads();
    if (tid < 64) {
        int grp = tid >> 2, k = tid & 3;
        float s = 0.f, q = 0.f;
        #pragma unroll
        for (int m = 0; m < 16; ++m) {
            int idx = (grp + 16*m)*4 + k;
            s += ls[idx]; q += lq[idx];
        }
        unsafeAtomicAdd(&sumout[tid], s);
        unsafeAtomicAdd(&sumout[64+tid], q);
    }
}

// 64x64 GEMM, bf16 input with fused BN (+relu).
template<bool RELU, bool AGG>
__global__ __launch_bounds__(256) void k_gemm64(
    const int* __restrict__ flag, const unsigned short* __restrict__ in,
    const void* __restrict__ W, const void* __restrict__ bias,
    const void* __restrict__ g, const void* __restrict__ bb,
    const float* __restrict__ insums, const float* __restrict__ dis,
    unsigned short* __restrict__ out_bf, float* __restrict__ outsums) {
    __shared__ __align__(16) float ws[64*64];
    __shared__ __align__(16) float xs[64*64];
    __shared__ float sc[64], sh[64];
    const int f = flag[0];
    const int tid = threadIdx.x;
    const int rowbase = blockIdx.x * 64;
    if (tid < 64) {
        float mean = insums[tid] * INV_N;
        float var  = fmaxf(insums[64+tid] * INV_N - mean*mean, 0.f);
        float s = ld1(g, tid, f) * rsqrtf(var + BN_EPS);
        sc[tid] = s;
        sh[tid] = ld1(bb, tid, f) - mean*s;
    }
    #pragma unroll
    for (int it = 0; it < 4; ++it) {
        int gi = it*256 + tid;
        float4 v = ld4(W, gi, f);
        int b = gi*4;
        ws[b]=v.x; ws[b+1]=v.y; ws[b+2]=v.z; ws[b+3]=v.w;
    }
    __syncthreads();
    {
        int row = tid & 63;
        int grow = rowbase + row;
        bool valid = grow < NN;
        #pragma unroll
        for (int it = 0; it < 4; ++it) {
            int f4 = (tid >> 6) + it*4;
            int k = f4*4;
            float a0=0,a1=0,a2=0,a3=0;
            if (valid) {
                ushort4 u = *(const ushort4*)&in[(size_t)grow*64 + k];
                a0=bf2f(u.x); a1=bf2f(u.y); a2=bf2f(u.z); a3=bf2f(u.w);
            }
            if (RELU) { a0=fmaxf(a0,0.f); a1=fmaxf(a1,0.f); a2=fmaxf(a2,0.f); a3=fmaxf(a3,0.f); }
            a0 = a0*sc[k+0]+sh[k+0]; a1 = a1*sc[k+1]+sh[k+1];
            a2 = a2*sc[k+2]+sh[k+2]; a3 = a3*sc[k+3]+sh[k+3];
            xs[(k+0)*64+row]=a0; xs[(k+1)*64+row]=a1;
            xs[(k+2)*64+row]=a2; xs[(k+3)*64+row]=a3;
        }
    }
    __syncthreads();
    const int tr = (tid >> 4) << 2;
    const int tc = (tid & 15) << 2;
    float acc[4][4] = {};
    #pragma unroll 8
    for (int k = 0; k < 64; ++k) {
        const float4 av = *(const float4*)&xs[k*64 + tr];
        const float4 wv = *(const float4*)&ws[k*64 + tc];
        const float aa[4] = {av.x, av.y, av.z, av.w};
        const float ww[4] = {wv.x, wv.y, wv.z, wv.w};
        #pragma unroll
        for (int i = 0; i < 4; ++i)
            #pragma unroll
            for (int j = 0; j < 4; ++j)
                acc[i][j] = fmaf(aa[i], ww[j], acc[i][j]);
    }
    float bc[4];
    #pragma unroll
    for (int j = 0; j < 4; ++j) bc[j] = ld1(bias, tc+j, f);
    if (AGG) {
        #pragma unroll
        for (int i = 0; i < 4; ++i) {
            int r = rowbase + tr + i;
            if (r < NN) {
                float hm = dis[r];
                ushort4 hv = make_ushort4(f2bf(acc[i][0]*hm), f2bf(acc[i][1]*hm),
                                          f2bf(acc[i][2]*hm), f2bf(acc[i][3]*hm));
                *(ushort4*)&out_bf[(size_t)r*64 + tc] = hv;
            }
        }
    } else {
        float ps[4] = {0,0,0,0}, pq[4] = {0,0,0,0};
        #pragma unroll
        for (int i = 0; i < 4; ++i) {
            int r = rowbase + tr + i;
            if (r < NN) {
                float y0 = acc[i][0]+bc[0], y1 = acc[i][1]+bc[1];
                float y2 = acc[i][2]+bc[2], y3 = acc[i][3]+bc[3];
                *(ushort4*)&out_bf[(size_t)r*64 + tc] =
                    make_ushort4(f2bf(y0), f2bf(y1), f2bf(y2), f2bf(y3));
                ps[0]+=y0; ps[1]+=y1; ps[2]+=y2; ps[3]+=y3;
                pq[0]+=y0*y0; pq[1]+=y1*y1; pq[2]+=y2*y2; pq[3]+=y3*y3;
            }
        }
        __syncthreads();
        int grp = tid >> 4;
        #pragma unroll
        for (int j = 0; j < 4; ++j) { xs[grp*64 + tc+j] = ps[j]; ws[grp*64 + tc+j] = pq[j]; }
        __syncthreads();
        if (tid < 64) {
            float s = 0.f, q = 0.f;
            #pragma unroll
            for (int g2 = 0; g2 < 16; ++g2) { s += xs[g2*64+tid]; q += ws[g2*64+tid]; }
            unsafeAtomicAdd(&outsums[tid], s);
            unsafeAtomicAdd(&outsums[64+tid], q);
        }
    }
}

// final: out = bn3(y3_bf16) @ lin2_W + lin2_b
__global__ __launch_bounds__(256) void k_final(
    const int* __restrict__ flag, const unsigned short* __restrict__ y3,
    const void* __restrict__ g, const void* __restrict__ bb,
    const float* __restrict__ sums, const void* __restrict__ w2,
    const void* __restrict__ b2, void* __restrict__ out) {
    __shared__ __align__(16) float tile[64*64];
    __shared__ float wp[64], tv[64];
    const int f = flag[0];
    const int tid = threadIdx.x;
    const int base = blockIdx.x * 64;
    if (tid < 64) {
        float mean = sums[tid] * INV_N;
        float var  = fmaxf(sums[64+tid] * INV_N - mean*mean, 0.f);
        float s = ld1(g, tid, f) * rsqrtf(var + BN_EPS);
        float t = ld1(bb, tid, f) - mean*s;
        float w = ld1(w2, tid, f);
        wp[tid] = s*w; tv[tid] = t*w;
    }
    #pragma unroll
    for (int it = 0; it < 4; ++it) {
        int i4 = it*256 + tid;
        int row = i4 >> 4, c4 = (i4 & 15)*4;
        float4 v = make_float4(0,0,0,0);
        if (base + row < NN) {
            ushort4 u = *(const ushort4*)&y3[(size_t)(base+row)*64 + c4];
            v = make_float4(bf2f(u.x), bf2f(u.y), bf2f(u.z), bf2f(u.w));
        }
        *(float4*)&tile[row*64 + c4] = v;
    }
    __syncthreads();
    if (tid < 64 && base + tid < NN) {
        float a = ld1(b2, 0, f);
        #pragma unroll
        for (int c = 0; c < 64; ++c) a += tv[c];
        #pragma unroll
        for (int cc = 0; cc < 64; ++cc) {
            int c = (cc + tid) & 63;
            a += tile[tid*64 + c] * wp[c];
        }
        if (f) ((float*)out)[base + tid] = a;
        else   ((unsigned short*)out)[base + tid] = f2bf(a);
    }
}

extern "C" void kernel_launch(void* const* d_in, const int* in_sizes, int n_in,
                              void* d_out, int out_size, void* d_ws, size_t ws_size,
                              hipStream_t stream) {
    const unsigned short* x = (const unsigned short*)d_in[0];
    const void* ew  = d_in[1];
    const void* W1  = d_in[2];
    const void* b1  = d_in[3];
    const void* W2  = d_in[4];
    const void* b2  = d_in[5];
    const void* l1W = d_in[6];
    const void* l1b = d_in[7];
    const void* l2W = d_in[8];
    const void* l2b = d_in[9];
    const void* g1  = d_in[10];
    const void* bb1 = d_in[11];
    const void* g2  = d_in[12];
    const void* bb2 = d_in[13];
    const void* g3  = d_in[14];
    const void* bb3 = d_in[15];
    const int* eidx = (const int*)d_in[16];

    // layout (float idx): flag 0, sums 16, dis 400;
    // region 100400..6500400: scr(int2) during preprocessing, then aggB (bf16)
    // hbuf(bf16) 6500400..9700400, histmat/rowptr 9700400, btot 10500656,
    // bstart 10502224, edata 10503792..13703792. Need 54.8 MB (proven).
    int*   flag = (int*)d_ws;
    float* wsf  = (float*)d_ws;
    float* sums = wsf + 16;
    float* dis  = wsf + 400;
    unsigned*       aggB = (unsigned*)(wsf + 100400);
    unsigned short* aggS = (unsigned short*)(wsf + 100400);
    unsigned short* hbuf = (unsigned short*)(wsf + 6500400);
    int*      histmat = (int*)(wsf + 9700400);
    int*      rowptr2 = histmat;
    int*      btot    = (int*)(wsf + 10500656);
    int*      bstart  = (int*)(wsf + 10502224);
    unsigned* edata   = (unsigned*)(wsf + 10503792);
    int2*     scr     = (int2*)(wsf + 100400);
    const size_t NEED = (size_t)13703792 * 4;
    if (ws_size < NEED) return;

    k_detect2  <<<1, 256, 0, stream>>>(x, eidx, flag, sums);
    k_hist     <<<NSB, 256, 0, stream>>>(flag, eidx, histmat);
    k_scanA    <<<NBK, 256, 0, stream>>>(histmat, btot);
    k_scanB    <<<1, 1024, 0, stream>>>(btot, bstart);
    k_scatter  <<<NSB, 256, 0, stream>>>(flag, eidx, ew, histmat, bstart, scr);
    k_sortdeg  <<<NBK, 256, 0, stream>>>(bstart, scr, edata, rowptr2, dis);
    // layer 1
    k_gemm1    <<<1563, 256, 0, stream>>>(flag, x, W1, b1, dis, hbuf);
    k_gather3  <<<NN/4, 256, 0, stream>>>(flag, rowptr2, bstart, edata,
                                          dis, b1, hbuf, aggB);
    k_bnstats_bf<<<512, 256, 0, stream>>>((const uint2*)aggB, sums + 0, 1);
    // layer 2
    k_gemm64<true, true><<<1563, 256, 0, stream>>>(flag, aggS, W2, b2, g1, bb1,
                                                   sums + 0, dis, hbuf, nullptr);
    k_gather3  <<<NN/4, 256, 0, stream>>>(flag, rowptr2, bstart, edata,
                                          dis, b2, hbuf, aggB);
    k_bnstats_bf<<<512, 256, 0, stream>>>((const uint2*)aggB, sums + 128, 0);
    // lin1 (+ bn3 stats), y3 bf16 in place over agg2
    k_gemm64<false, false><<<1563, 256, 0, stream>>>(flag, aggS, l1W, l1b, g2, bb2,
                                                     sums + 128, dis, aggS, sums + 256);
    k_final    <<<1563, 256, 0, stream>>>(flag, aggS, g3, bb3, sums + 256, l2W, l2b, d_out);
}